// Round 16
// baseline (259.870 us; speedup 1.0000x reference)
//
#include <hip/hip_runtime.h>
#include <hip/hip_bf16.h>

// MLA prefill: B=2,S=2048,DIM=2048,NH=16,D_NOPE=128,D_ROPE=64,D_V=128,KV_RANK=512
// R19: attn gets the T15 att[2] deferred-softmax pipeline (m214v36: +7-11%
// on attention): at iter t, issue QK(t) MFMAs, then run tile t-1's deferred
// exp/sum/pack/PV (independent regs) under them; then mask/max/defer-max(t).
// V LDS ring 2->3 (V(t-1) read one iter later; 104KB, still 1 block/CU);
// K stays 2-ring; per-wave have_prev/sp/vtp with causal-exit + item-end flush.
// Ledger: write(t+1) targets K[(u+1)&1] (last read iter t-1) and V[(u+1)%3]
// (last read by deferred PV(t-2) at iter t-1) -> both >=1 barrier ago.
// GEMMs/casts/rope_rms/combine identical to R18 (245.8us best).

typedef __bf16 bf16x8 __attribute__((ext_vector_type(8)));
typedef float  f32x4  __attribute__((ext_vector_type(4)));
typedef float  f32x16 __attribute__((ext_vector_type(16)));
typedef unsigned short us8 __attribute__((ext_vector_type(8)));
typedef unsigned short us4 __attribute__((ext_vector_type(4)));
typedef unsigned int   ui4 __attribute__((ext_vector_type(4)));

#define S_LEN   2048
#define BS_TOT  4096   // B*S
#define NH      16
#define DQK     192
#define DV      128
#define KV_RANK 512
#define QSTR    3840   // fused q|kv_a row stride (3072 + 640 + 128 pad)

__device__ inline unsigned short f2bf(float f) {
  __hip_bfloat16 h = __float2bfloat16(f);
  return *reinterpret_cast<unsigned short*>(&h);
}
__device__ inline float bfu2f(unsigned short u) {
  unsigned int x = ((unsigned int)u) << 16;
  return __builtin_bit_cast(float, x);
}
__device__ inline unsigned int pack2bf(float a, float b) {
  return (unsigned int)f2bf(a) | ((unsigned int)f2bf(b) << 16);
}
__device__ inline void glds16(const void* g, void* l) {
  __builtin_amdgcn_global_load_lds(
      (const __attribute__((address_space(1))) unsigned int*)g,
      (__attribute__((address_space(3))) unsigned int*)l, 16, 0, 0);
}

// ---------------- fused f32 -> bf16 casts (5 segments, 1 launch) --------------
__global__ __launch_bounds__(256) void cast_all_kernel(
    const float* __restrict__ x, const float* __restrict__ wq,
    const float* __restrict__ wkva, const float* __restrict__ wkvb,
    const float* __restrict__ wo,
    __hip_bfloat16* __restrict__ xb, __hip_bfloat16* __restrict__ wqb,
    __hip_bfloat16* __restrict__ wkvab, __hip_bfloat16* __restrict__ wkvbb,
    __hip_bfloat16* __restrict__ wob) {
  const int bid = blockIdx.x;
  const float* src; __hip_bfloat16* dst; int n, npad, b0, nb;
  if (bid < 771)       { src = x;    dst = xb;    n = 8388608; npad = 8388608; b0 = 0;    nb = 771; }
  else if (bid < 1349) { src = wq;   dst = wqb;   n = 6291456; npad = 6291456; b0 = 771;  nb = 578; }
  else if (bid < 1469) { src = wkva; dst = wkvab; n = 1179648; npad = 1572864; b0 = 1349; nb = 120; }
  else if (bid < 1662) { src = wkvb; dst = wkvbb; n = 2097152; npad = 2097152; b0 = 1469; nb = 193; }
  else                 { src = wo;   dst = wob;   n = 4194304; npad = 4194304; b0 = 1662; nb = 386; }
  const int tid = (bid - b0) * 256 + threadIdx.x;
  const int stride = nb * 256;
  for (int i = tid * 4; i < npad; i += stride * 4) {
    if (i + 3 < n) {
      f32x4 v = *(const f32x4*)(src + i);
      dst[i + 0] = __float2bfloat16(v.x);
      dst[i + 1] = __float2bfloat16(v.y);
      dst[i + 2] = __float2bfloat16(v.z);
      dst[i + 3] = __float2bfloat16(v.w);
    } else {
#pragma unroll
      for (int z = 0; z < 4; z++)
        dst[i + z] = __float2bfloat16((i + z < n) ? src[i + z] : 0.f);
    }
  }
}

// ------------- 256x256 8-wave pipelined GEMM (R13, known-good) ----------------
template<int OUT_BF16>
__global__ __launch_bounds__(512, 2) void gemm_bt256(
    const __hip_bfloat16* __restrict__ A, const __hip_bfloat16* __restrict__ Bw,
    void* __restrict__ Cp, int M, int N, int K, int nbx) {
  __shared__ alignas(16) unsigned short Asl[2][256 * 64];  // 64 KB
  __shared__ alignas(16) unsigned short Bsl[2][256 * 64];  // 64 KB

  const int nwg = gridDim.x;
  const int cpx = nwg >> 3;
  const int id  = (blockIdx.x & 7) * cpx + (blockIdx.x >> 3);  // XCD chunking
  const int bx = id % nbx, by = id / nbx;
  const int m0 = by * 256, n0 = bx * 256;

  const int tid = threadIdx.x, w = tid >> 6, lane = tid & 63;
  const int wr = w >> 2, wc = w & 3;
  const int ml = lane & 15, quad = lane >> 4;
  const int srow = w * 8 + (lane >> 3);
  const int scol = ((lane & 7) ^ (lane >> 3)) * 8;  // pre-swizzled source chunk

  const unsigned short* Ag = (const unsigned short*)A + (size_t)(m0 + srow) * K + scol;
  const unsigned short* Bg = (const unsigned short*)Bw + (size_t)(n0 + srow) * K + scol;

  f32x4 acc[8][4];
#pragma unroll
  for (int i = 0; i < 8; i++)
#pragma unroll
    for (int j = 0; j < 4; j++)
#pragma unroll
      for (int e = 0; e < 4; e++) acc[i][j][e] = 0.0f;

  auto stage = [&](int slot, int k0) {
#pragma unroll
    for (int j = 0; j < 4; j++)
      glds16(Ag + (size_t)j * 64 * K + k0, &Asl[slot][(j * 64 + w * 8) * 64]);
#pragma unroll
    for (int j = 0; j < 4; j++)
      glds16(Bg + (size_t)j * 64 * K + k0, &Bsl[slot][(j * 64 + w * 8) * 64]);
  };

  const int nt = K / 64;
  stage(0, 0);
  stage(1, 64);
  asm volatile("s_waitcnt vmcnt(8)" ::: "memory");
  __builtin_amdgcn_s_barrier();
  asm volatile("" ::: "memory");

  int slot = 0;
  for (int t = 0; t < nt; ++t) {
    const unsigned short* As = &Asl[slot][0];
    const unsigned short* Bs = &Bsl[slot][0];

    bf16x8 bfr[2][2][2];
#pragma unroll
    for (int nh = 0; nh < 2; nh++)
#pragma unroll
      for (int nf = 0; nf < 2; nf++) {
        int r = wc * 64 + nh * 32 + nf * 16 + ml;
        const char* rowp = (const char*)&Bs[r * 64];
#pragma unroll
        for (int ks = 0; ks < 2; ks++)
          bfr[nh][nf][ks] =
              *(const bf16x8*)(rowp + ((ks * 64 + quad * 16) ^ ((ml & 7) << 4)));
      }
#pragma unroll
    for (int mh = 0; mh < 2; mh++) {
      bf16x8 af[4][2];
#pragma unroll
      for (int mf = 0; mf < 4; mf++) {
        int r = wr * 128 + mh * 64 + mf * 16 + ml;
        const char* rowp = (const char*)&As[r * 64];
#pragma unroll
        for (int ks = 0; ks < 2; ks++)
          af[mf][ks] =
              *(const bf16x8*)(rowp + ((ks * 64 + quad * 16) ^ ((ml & 7) << 4)));
      }
      __builtin_amdgcn_s_setprio(1);
#pragma unroll
      for (int nh = 0; nh < 2; nh++)
#pragma unroll
        for (int mf = 0; mf < 4; mf++)
#pragma unroll
          for (int nf = 0; nf < 2; nf++)
#pragma unroll
            for (int ks = 0; ks < 2; ks++)
              acc[mh * 4 + mf][nh * 2 + nf] = __builtin_amdgcn_mfma_f32_16x16x32_bf16(
                  af[mf][ks], bfr[nh][nf][ks], acc[mh * 4 + mf][nh * 2 + nf], 0, 0, 0);
      __builtin_amdgcn_s_setprio(0);
    }

    asm volatile("" ::: "memory");
    __builtin_amdgcn_s_barrier();
    asm volatile("" ::: "memory");
    if (t + 2 < nt) {
      stage(slot, (t + 2) * 64);
      asm volatile("s_waitcnt vmcnt(8)" ::: "memory");
    } else {
      asm volatile("s_waitcnt vmcnt(0)" ::: "memory");
    }
    __builtin_amdgcn_s_barrier();
    asm volatile("" ::: "memory");
    slot ^= 1;
  }

#pragma unroll
  for (int mi = 0; mi < 8; mi++) {
#pragma unroll
    for (int ni = 0; ni < 4; ni++) {
      int col = n0 + wc * 64 + ni * 16 + ml;
      int rowb = m0 + wr * 128 + mi * 16 + quad * 4;
#pragma unroll
      for (int j = 0; j < 4; j++) {
        float v = acc[mi][ni][j];
        if (OUT_BF16)
          ((__hip_bfloat16*)Cp)[(size_t)(rowb + j) * N + col] = __float2bfloat16(v);
        else
          ((float*)Cp)[(size_t)(rowb + j) * N + col] = v;
      }
    }
  }
}

// ---- 256x128-tile variant (same template; BN=128): grid (N/128)*(M/256) -----
template<int OUT_BF16>
__global__ __launch_bounds__(512, 1) void gemm_bt256x128(
    const __hip_bfloat16* __restrict__ A, const __hip_bfloat16* __restrict__ Bw,
    void* __restrict__ Cp, int M, int N, int K, int nbx) {
  __shared__ alignas(16) unsigned short Asl[2][256 * 64];  // 64 KB
  __shared__ alignas(16) unsigned short Bsl[2][128 * 64];  // 32 KB

  const int nwg = gridDim.x;
  const int cpx = nwg >> 3;
  const int id  = (blockIdx.x & 7) * cpx + (blockIdx.x >> 3);  // XCD chunking
  const int bx = id % nbx, by = id / nbx;
  const int m0 = by * 256, n0 = bx * 128;

  const int tid = threadIdx.x, w = tid >> 6, lane = tid & 63;
  const int wr = w >> 2, wc = w & 3;            // 2(M) x 4(N); wave covers 128x32
  const int ml = lane & 15, quad = lane >> 4;
  const int srow = w * 8 + (lane >> 3);
  const int scol = ((lane & 7) ^ (lane >> 3)) * 8;  // pre-swizzled source chunk

  const unsigned short* Ag = (const unsigned short*)A + (size_t)(m0 + srow) * K + scol;
  const unsigned short* Bg = (const unsigned short*)Bw + (size_t)(n0 + srow) * K + scol;

  f32x4 acc[8][2];
#pragma unroll
  for (int i = 0; i < 8; i++)
#pragma unroll
    for (int j = 0; j < 2; j++)
#pragma unroll
      for (int e = 0; e < 4; e++) acc[i][j][e] = 0.0f;

  auto stage = [&](int slot, int k0) {
#pragma unroll
    for (int j = 0; j < 4; j++)
      glds16(Ag + (size_t)j * 64 * K + k0, &Asl[slot][(j * 64 + w * 8) * 64]);
#pragma unroll
    for (int j = 0; j < 2; j++)
      glds16(Bg + (size_t)j * 64 * K + k0, &Bsl[slot][(j * 64 + w * 8) * 64]);
  };

  const int nt = K / 64;
  stage(0, 0);
  stage(1, 64);
  asm volatile("s_waitcnt vmcnt(6)" ::: "memory");  // slot0 (oldest 6) landed
  __builtin_amdgcn_s_barrier();
  asm volatile("" ::: "memory");

  int slot = 0;
  for (int t = 0; t < nt; ++t) {
    const unsigned short* As = &Asl[slot][0];
    const unsigned short* Bs = &Bsl[slot][0];

    bf16x8 bfr[2][2];  // [nf][ks]; wave cols = wc*32 + nf*16 + ml
#pragma unroll
    for (int nf = 0; nf < 2; nf++) {
      int r = wc * 32 + nf * 16 + ml;
      const char* rowp = (const char*)&Bs[r * 64];
#pragma unroll
      for (int ks = 0; ks < 2; ks++)
        bfr[nf][ks] =
            *(const bf16x8*)(rowp + ((ks * 64 + quad * 16) ^ ((ml & 7) << 4)));
    }
#pragma unroll
    for (int mh = 0; mh < 2; mh++) {
      bf16x8 af[4][2];
#pragma unroll
      for (int mf = 0; mf < 4; mf++) {
        int r = wr * 128 + mh * 64 + mf * 16 + ml;
        const char* rowp = (const char*)&As[r * 64];
#pragma unroll
        for (int ks = 0; ks < 2; ks++)
          af[mf][ks] =
              *(const bf16x8*)(rowp + ((ks * 64 + quad * 16) ^ ((ml & 7) << 4)));
      }
      __builtin_amdgcn_s_setprio(1);
#pragma unroll
      for (int mf = 0; mf < 4; mf++)
#pragma unroll
        for (int nf = 0; nf < 2; nf++)
#pragma unroll
          for (int ks = 0; ks < 2; ks++)
            acc[mh * 4 + mf][nf] = __builtin_amdgcn_mfma_f32_16x16x32_bf16(
                af[mf][ks], bfr[nf][ks], acc[mh * 4 + mf][nf], 0, 0, 0);
      __builtin_amdgcn_s_setprio(0);
    }

    asm volatile("" ::: "memory");
    __builtin_amdgcn_s_barrier();
    asm volatile("" ::: "memory");
    if (t + 2 < nt) {
      stage(slot, (t + 2) * 64);
      asm volatile("s_waitcnt vmcnt(6)" ::: "memory");
    } else {
      asm volatile("s_waitcnt vmcnt(0)" ::: "memory");
    }
    __builtin_amdgcn_s_barrier();
    asm volatile("" ::: "memory");
    slot ^= 1;
  }

#pragma unroll
  for (int mi = 0; mi < 8; mi++) {
#pragma unroll
    for (int ni = 0; ni < 2; ni++) {
      int col = n0 + wc * 32 + ni * 16 + ml;
      int rowb = m0 + wr * 128 + mi * 16 + quad * 4;
#pragma unroll
      for (int j = 0; j < 4; j++) {
        float v = acc[mi][ni][j];
        if (OUT_BF16)
          ((__hip_bfloat16*)Cp)[(size_t)(rowb + j) * N + col] = __float2bfloat16(v);
        else
          ((float*)Cp)[(size_t)(rowb + j) * N + col] = v;
      }
    }
  }
}

// --- merged: RoPE(q_pe) in place + RMSNorm(kv latent) + RoPE(k_pe) -----------
__global__ __launch_bounds__(256) void rope_rms_kernel(
    __hip_bfloat16* __restrict__ qkv, const float* __restrict__ w,
    const float* __restrict__ freqs, __hip_bfloat16* __restrict__ latent,
    __hip_bfloat16* __restrict__ kpe_out) {
  int si = blockIdx.x;
  int s  = si & (S_LEN - 1);
  int tid = threadIdx.x;
#pragma unroll
  for (int p = tid; p < NH * 32; p += 256) {
    int h = p >> 5, i = p & 31;
    size_t base = (size_t)si * QSTR + h * DQK + 128 + 2 * i;
    float c  = freqs[s * 64 + 2 * i];
    float sn = freqs[s * 64 + 2 * i + 1];
    float x0 = __bfloat162float(qkv[base]);
    float x1 = __bfloat162float(qkv[base + 1]);
    qkv[base]     = __float2bfloat16(x0 * c - x1 * sn);
    qkv[base + 1] = __float2bfloat16(x0 * sn + x1 * c);
  }
  const unsigned short* row = (const unsigned short*)qkv + (size_t)si * QSTR + 3072;
  float v0 = bfu2f(row[tid]), v1 = bfu2f(row[tid + 256]);
  float ss = v0 * v0 + v1 * v1;
#pragma unroll
  for (int off = 1; off < 64; off <<= 1) ss += __shfl_xor(ss, off, 64);
  __shared__ float red[4];
  if ((tid & 63) == 0) red[tid >> 6] = ss;
  __syncthreads();
  float tot = red[0] + red[1] + red[2] + red[3];
  float r = rsqrtf(tot / 512.0f + 1e-6f);
  latent[(size_t)si * 512 + tid]       = __float2bfloat16(v0 * r * w[tid]);
  latent[(size_t)si * 512 + tid + 256] = __float2bfloat16(v1 * r * w[tid + 256]);
  if (tid < 32) {
    float c  = freqs[s * 64 + 2 * tid];
    float sn = freqs[s * 64 + 2 * tid + 1];
    float x0 = bfu2f(row[512 + 2 * tid]), x1 = bfu2f(row[512 + 2 * tid + 1]);
    kpe_out[(size_t)si * 64 + 2 * tid]     = __float2bfloat16(x0 * c - x1 * sn);
    kpe_out[(size_t)si * 64 + 2 * tid + 1] = __float2bfloat16(x0 * sn + x1 * c);
  }
}

// ------ 32x32-fragment MFMA flash attention + T15 deferred-softmax ------------
__global__ __launch_bounds__(512, 2) void attn_mfma_kernel(
    const __hip_bfloat16* __restrict__ qb,    // fused qkv [BS][QSTR]
    const __hip_bfloat16* __restrict__ kvup,  // [BS][NH*256] (nope|v per head)
    const __hip_bfloat16* __restrict__ kpe,   // [BS][64] bf16
    unsigned short* __restrict__ op0,         // partial O half0 [BS][NH][128] bf16
    unsigned short* __restrict__ op1,         // partial O half1
    float* __restrict__ mlp0,                 // [BS*NH][2] {m,l} half0
    float* __restrict__ mlp1) {               // half1
  constexpr int KS = 200;
  constexpr int VS = 36;
  __shared__ alignas(16) unsigned short Ks[2][64 * KS];   // 51200 B
  __shared__ alignas(16) unsigned int   Vt3[3][128 * VS]; // 55296 B

  const int id = blockIdx.x;
  const int x  = id >> 5;
  const int hb = id & 31;
  const int h  = hb >> 1, b = hb & 1;

  const int tid = threadIdx.x, wave = tid >> 6, lane = tid & 63;
  const int l31 = lane & 31, hh = lane >> 5;
  const float qs2 = 0.07216878364870322f * 1.4426950408889634f;  // scale*log2e

  const int m16 = tid & 15;
  const int hp  = tid >> 4;
  const int vkey = (m16 & 7) << 2;
  const unsigned short* kvbase = (const unsigned short*)kvup;
  const unsigned short* kpbase = (const unsigned short*)kpe;

  int kr_[3], kc_[3];
#pragma unroll
  for (int it = 0; it < 3; it++) {
    int slot = tid + it * 512;
    kr_[it] = slot / 24;
    kc_[it] = slot - kr_[it] * 24;
  }

#pragma unroll 1
  for (int item = 0; item < 2; ++item) {
    const int qt2    = item ? (7 - x) : x;
    const int kstart = item ? (2 * qt2 + 2) : 0;
    const int kend   = kstart + 2 * qt2 + 2;
    const int qwb = qt2 * 256 + wave * 32;
    const int qg  = qwb + l31;

    bf16x8 Qf[12];
    {
      const unsigned short* qrow = (const unsigned short*)qb +
          (size_t)(b * S_LEN + qg) * QSTR + h * DQK;
#pragma unroll
      for (int s = 0; s < 12; s++)
        Qf[s] = *(const bf16x8*)(qrow + s * 16 + hh * 8);
    }

    float m_i = -1e30f, l_i = 0.0f;
    f32x16 O2[4];
#pragma unroll
    for (int mt = 0; mt < 4; mt++)
#pragma unroll
      for (int j = 0; j < 16; j++) O2[mt][j] = 0.0f;

    us8 Kpre[3], Vpre[2];

    const unsigned short* kptr[3];
    int kstep[3];
#pragma unroll
    for (int it = 0; it < 3; it++) {
      if (kc_[it] < 16) {
        kptr[it] = kvbase + (size_t)(b * S_LEN + kstart * 64 + kr_[it]) * (NH * 256)
                   + h * 256 + kc_[it] * 8;
        kstep[it] = 64 * NH * 256;
      } else {
        kptr[it] = kpbase + (size_t)(b * S_LEN + kstart * 64 + kr_[it]) * 64
                   + (kc_[it] - 16) * 8;
        kstep[it] = 64 * 64;
      }
    }
    const unsigned short* vptr = kvbase +
        (size_t)(b * S_LEN + kstart * 64 + 2 * hp) * (NH * 256) + h * 256 + 128 + m16 * 8;

    if (item) __syncthreads();

    // ---- prologue: load tile kstart, write K slot0 + V slot0, barrier ----
    {
#pragma unroll
      for (int it = 0; it < 3; it++) {
        Kpre[it] = *(const us8*)kptr[it];
        kptr[it] += kstep[it];
      }
      Vpre[0] = *(const us8*)vptr;
      Vpre[1] = *(const us8*)(vptr + NH * 256);
      vptr += 64 * NH * 256;
#pragma unroll
      for (int it = 0; it < 3; it++)
        *(us8*)&Ks[0][kr_[it] * KS + kc_[it] * 8] = Kpre[it];
#pragma unroll
      for (int z = 0; z < 8; z++) {
        int d = m16 * 8 + z;
        Vt3[0][d * VS + (hp ^ vkey)] =
            (unsigned)(unsigned short)Vpre[0][z] |
            ((unsigned)(unsigned short)Vpre[1][z] << 16);
      }
      __syncthreads();
    }

    // ---- T15 deferred-softmax state ----
    bool have_prev = false;
    f32x16 sp[2];               // prev tile's masked RAW scores
    const unsigned int* vtp = &Vt3[0][0];

    // finish tile t-1: exp (at current m_i), sum->l, pack, PV from vtp
    auto finish_prev = [&]() {
      const float nm = -m_i;
#pragma unroll
      for (int mt = 0; mt < 2; mt++)
#pragma unroll
        for (int r = 0; r < 16; r++)
          sp[mt][r] = exp2f(fmaf(sp[mt][r], qs2, nm));
      float s16[16];
#pragma unroll
      for (int r = 0; r < 16; r++) s16[r] = sp[0][r] + sp[1][r];
#pragma unroll
      for (int sw = 8; sw >= 1; sw >>= 1)
#pragma unroll
        for (int r = 0; r < 8; r++)
          if (r < sw) s16[r] += s16[r + sw];
      float psum = s16[0];
      psum += __shfl_xor(psum, 32, 64);
      l_i += psum;

      bf16x8 pf[4];
#pragma unroll
      for (int ss = 0; ss < 4; ss++) {
        const int pmt = ss >> 1, gg = ss & 1;
        unsigned int U0 = pack2bf(sp[pmt][gg * 8 + 0], sp[pmt][gg * 8 + 1]);
        unsigned int U1 = pack2bf(sp[pmt][gg * 8 + 2], sp[pmt][gg * 8 + 3]);
        unsigned int U2 = pack2bf(sp[pmt][gg * 8 + 4], sp[pmt][gg * 8 + 5]);
        unsigned int U3 = pack2bf(sp[pmt][gg * 8 + 6], sp[pmt][gg * 8 + 7]);
        unsigned int E0 = __shfl_xor(hh ? U0 : U2, 32, 64);
        unsigned int E1 = __shfl_xor(hh ? U1 : U3, 32, 64);
        ui4 pd;
        pd.x = hh ? E0 : U0;
        pd.y = hh ? E1 : U1;
        pd.z = hh ? U2 : E0;
        pd.w = hh ? U3 : E1;
        pf[ss] = __builtin_bit_cast(bf16x8, pd);
      }
      __builtin_amdgcn_s_setprio(1);
#pragma unroll
      for (int ss = 0; ss < 4; ss++) {
#pragma unroll
        for (int mt = 0; mt < 4; mt++) {
          int v = mt * 32 + l31;
          const unsigned int* vp =
              &vtp[v * VS + ((ss * 8 + hh * 4) ^ (((v >> 3) & 7) << 2))];
          bf16x8 bv = *(const bf16x8*)vp;
          O2[mt] = __builtin_amdgcn_mfma_f32_32x32x16_bf16(bv, pf[ss], O2[mt],
                                                           0, 0, 0);
        }
      }
      __builtin_amdgcn_s_setprio(0);
    };

    for (int kt = kstart; kt < kend; kt++) {
      const int u  = kt - kstart;
      const int kb = kt * 64;
      const unsigned short* ksc = Ks[u & 1];
      const unsigned int*   vtc = &Vt3[u % 3][0];

      const int havenext = (kt + 1 < kend);
      if (havenext) {
#pragma unroll
        for (int it = 0; it < 3; it++) {
          Kpre[it] = *(const us8*)kptr[it];
          kptr[it] += kstep[it];
        }
        Vpre[0] = *(const us8*)vptr;
        Vpre[1] = *(const us8*)(vptr + NH * 256);
        vptr += 64 * NH * 256;
      }

      if (kb <= qwb + 31) {
        // 1. QK(t) -> st2 (MFMA; results consumed only at step 3)
        f32x16 st2[2];
        __builtin_amdgcn_s_setprio(1);
#pragma unroll
        for (int mt = 0; mt < 2; mt++) {
          f32x16 acc;
#pragma unroll
          for (int j = 0; j < 16; j++) acc[j] = 0.0f;
#pragma unroll
          for (int s = 0; s < 12; s++) {
            bf16x8 kf = *(const bf16x8*)&ksc[(mt * 32 + l31) * KS + s * 16 + hh * 8];
            acc = __builtin_amdgcn_mfma_f32_32x32x16_bf16(kf, Qf[s], acc, 0, 0, 0);
          }
          st2[mt] = acc;
        }
        __builtin_amdgcn_s_setprio(0);

        // 2. deferred finish of tile t-1 (independent of st2 -> overlaps QK)
        if (have_prev) finish_prev();

        // 3. mask(t) in RAW domain, tree max, defer-max m/O/l update
        if (kb + 64 > qwb) {
#pragma unroll
          for (int mt = 0; mt < 2; mt++)
#pragma unroll
            for (int r = 0; r < 16; r++) {
              int kpos = kb + mt * 32 + (r & 3) + 8 * (r >> 2) + 4 * hh;
              st2[mt][r] = (kpos > qg) ? -1e30f : st2[mt][r];
            }
        }
        float t16[16];
#pragma unroll
        for (int r = 0; r < 16; r++) t16[r] = fmaxf(st2[0][r], st2[1][r]);
#pragma unroll
        for (int sw = 8; sw >= 1; sw >>= 1)
#pragma unroll
          for (int r = 0; r < 8; r++)
            if (r < sw) t16[r] = fmaxf(t16[r], t16[r + sw]);
        float mloc = t16[0] * qs2;
        mloc = fmaxf(mloc, __shfl_xor(mloc, 32, 64));
        if (!__all(mloc <= m_i + 8.0f)) {
          float m_new = fmaxf(m_i, mloc);
          float alpha = exp2f(m_i - m_new);
          l_i *= alpha;
#pragma unroll
          for (int mt = 0; mt < 4; mt++)
#pragma unroll
            for (int j = 0; j < 16; j++) O2[mt][j] *= alpha;
          m_i = m_new;
        }

        // 4. hand off tile t as the new prev
        sp[0] = st2[0];
        sp[1] = st2[1];
        vtp = vtc;
        have_prev = true;
      } else if (have_prev) {
        finish_prev();        // wave exited causal range: flush
        have_prev = false;
      }

      if (havenext) {
        // write K(t+1) -> K[(u+1)&1] (last read iter t-1); V(t+1) -> V[(u+1)%3]
        // (last read by deferred PV(t-2) at iter t-1) — both >=1 barrier ago.
#pragma unroll
        for (int it = 0; it < 3; it++)
          *(us8*)&Ks[(u + 1) & 1][kr_[it] * KS + kc_[it] * 8] = Kpre[it];
        unsigned int* vtn = &Vt3[(u + 1) % 3][0];
#pragma unroll
        for (int z = 0; z < 8; z++) {
          int d = m16 * 8 + z;
          vtn[d * VS + (hp ^ vkey)] =
              (unsigned)(unsigned short)Vpre[0][z] |
              ((unsigned)(unsigned short)Vpre[1][z] << 16);
        }
        __syncthreads();
      }
    }

    if (have_prev) {          // item tail flush
      finish_prev();
      have_prev = false;
    }

    // ---- partial epilogue ----
    unsigned short* op = item ? op1 : op0;
    float* mlp = item ? mlp1 : mlp0;
    const size_t basep = (size_t)(b * S_LEN + qg) * NH + h;
    unsigned short* orow = op + basep * 128;
#pragma unroll
    for (int mt = 0; mt < 4; mt++) {
#pragma unroll
      for (int g = 0; g < 4; g++) {
        us4 pk;
#pragma unroll
        for (int j = 0; j < 4; j++) pk[j] = f2bf(O2[mt][g * 4 + j]);
        *(us4*)(orow + mt * 32 + g * 8 + hh * 4) = pk;
      }
    }
    if (hh == 0) {
      mlp[basep * 2 + 0] = m_i;
      mlp[basep * 2 + 1] = l_i;
    }
  }
}

// ---------------- combine the two K-halves per q-row ---------------------------
__global__ __launch_bounds__(256) void attn_combine_kernel(
    const unsigned short* __restrict__ op0, const unsigned short* __restrict__ op1,
    const float* __restrict__ mlp0, const float* __restrict__ mlp1,
    __hip_bfloat16* __restrict__ attn_out) {
  const int bs = blockIdx.x;
  const int tid = threadIdx.x;
  const int h = tid >> 4, dc = (tid & 15) * 8;
  const size_t basep = (size_t)bs * NH + h;
  const us8 a = *(const us8*)(op0 + basep * 128 + dc);
  const us8 c = *(const us8*)(op1 + basep * 128 + dc);
  const float m0 = mlp0[basep * 2], l0 = mlp0[basep * 2 + 1];
  const float m1 = mlp1[basep * 2], l1 = mlp1[basep * 2 + 1];
  const float m = fmaxf(m0, m1);
  const float a0 = exp2f(m0 - m), a1 = exp2f(m1 - m);
  const float inv = 1.0f / (l0 * a0 + l1 * a1);
  us8 o;
#pragma unroll
  for (int z = 0; z < 8; z++) {
    float v = (bfu2f((unsigned short)a[z]) * a0 +
               bfu2f((unsigned short)c[z]) * a1) * inv;
    o[z] = f2bf(v);
  }
  *(us8*)((unsigned short*)attn_out + (size_t)bs * (NH * DV) + h * DV + dc) = o;
}

// ---------------- launch ----------------
extern "C" void kernel_launch(void* const* d_in, const int* in_sizes, int n_in,
                              void* d_out, int out_size, void* d_ws, size_t ws_size,
                              hipStream_t stream) {
  const float* x     = (const float*)d_in[0];
  const float* freqs = (const float*)d_in[2];
  const float* wq    = (const float*)d_in[4];
  const float* wkva  = (const float*)d_in[5];
  const float* wkvb  = (const float*)d_in[6];
  const float* wo    = (const float*)d_in[7];
  const float* kvnw  = (const float*)d_in[8];
  float* out = (float*)d_out;

  char* ws = (char*)d_ws;
  size_t off = 0;
  auto alloc = [&](size_t bytes) {
    void* p = ws + off;
    off += (bytes + 255) & ~(size_t)255;
    return p;
  };
  __hip_bfloat16* x_bf    = (__hip_bfloat16*)alloc((size_t)BS_TOT * 2048 * 2);
  __hip_bfloat16* wq_bf   = (__hip_bfloat16*)alloc((size_t)3072 * 2048 * 2);
  __hip_bfloat16* wkva_bf = (__hip_bfloat16*)alloc((size_t)768 * 2048 * 2);  // contiguous with wq_bf -> 3840 rows
  __hip_bfloat16* wkvb_bf = (__hip_bfloat16*)alloc((size_t)4096 * 512 * 2);
  __hip_bfloat16* wo_bf   = (__hip_bfloat16*)alloc((size_t)2048 * 2048 * 2);
  __hip_bfloat16* qkv_bf  = (__hip_bfloat16*)alloc((size_t)BS_TOT * QSTR * 2);
  __hip_bfloat16* latent  = (__hip_bfloat16*)alloc((size_t)BS_TOT * 512 * 2);
  __hip_bfloat16* kpe     = (__hip_bfloat16*)alloc((size_t)BS_TOT * 64 * 2);
  __hip_bfloat16* kvup    = (__hip_bfloat16*)alloc((size_t)BS_TOT * 4096 * 2);
  __hip_bfloat16* attn    = (__hip_bfloat16*)alloc((size_t)BS_TOT * 2048 * 2);

  unsigned short* op0 = (unsigned short*)x_bf;
  unsigned short* op1 = (unsigned short*)wq_bf;
  float* mlp0 = (float*)latent;
  float* mlp1 = mlp0 + (size_t)BS_TOT * NH * 2;

  cast_all_kernel<<<2048, 256, 0, stream>>>(x, wq, wkva, wkvb, wo,
                                            x_bf, wq_bf, wkva_bf, wkvb_bf, wo_bf);

  gemm_bt256<1><<<dim3(240), 512, 0, stream>>>(
      x_bf, wq_bf, qkv_bf, BS_TOT, QSTR, 2048, QSTR / 256);
  rope_rms_kernel<<<BS_TOT, 256, 0, stream>>>(qkv_bf, kvnw, freqs, latent, kpe);

  gemm_bt256<1><<<dim3(256), 512, 0, stream>>>(
      latent, wkvb_bf, kvup, BS_TOT, 4096, 512, 16);

  attn_mfma_kernel<<<dim3(256, 1, 1), 512, 0, stream>>>(
      qkv_bf, kvup, kpe, op0, op1, mlp0, mlp1);
  attn_combine_kernel<<<dim3(BS_TOT, 1, 1), 256, 0, stream>>>(
      op0, op1, mlp0, mlp1, attn);

  gemm_bt256x128<0><<<dim3(256), 512, 0, stream>>>(
      attn, wo_bf, out, BS_TOT, 2048, 2048, 16);
}

// Round 17
// 245.775 us; speedup vs baseline: 1.0574x; 1.0574x over previous
//
#include <hip/hip_runtime.h>
#include <hip/hip_bf16.h>

// MLA prefill: B=2,S=2048,DIM=2048,NH=16,D_NOPE=128,D_ROPE=64,D_V=128,KV_RANK=512
// R20: byte-exact revert to R18 (245.8us, session best). R19's T15 deferred-
// softmax regressed attn 82.6->94.5us (same-wave MFMA can't hide under MFMA;
// 3-ring V raised FETCH 55->67MB) -> reverted. Lever ledger: attn VALU cuts
// (null), attn occupancy x2 (null), T15 (-12us), GEMM 8-phase x2 (regressed),
// wo 256x128 tile packing (+15us, kept). Config: R13 coarse counted-vmcnt
// 256x256 GEMM (qkv/kvup) + 256x128 (wo), R14 attn (split-K balanced, raw-
// domain mask, FMA exp2, tree reductions, defer-max), fused casts, merged
// rope_rms, partials+combine.

typedef __bf16 bf16x8 __attribute__((ext_vector_type(8)));
typedef float  f32x4  __attribute__((ext_vector_type(4)));
typedef float  f32x16 __attribute__((ext_vector_type(16)));
typedef unsigned short us8 __attribute__((ext_vector_type(8)));
typedef unsigned short us4 __attribute__((ext_vector_type(4)));
typedef unsigned int   ui4 __attribute__((ext_vector_type(4)));

#define S_LEN   2048
#define BS_TOT  4096   // B*S
#define NH      16
#define DQK     192
#define DV      128
#define KV_RANK 512
#define QSTR    3840   // fused q|kv_a row stride (3072 + 640 + 128 pad)

__device__ inline unsigned short f2bf(float f) {
  __hip_bfloat16 h = __float2bfloat16(f);
  return *reinterpret_cast<unsigned short*>(&h);
}
__device__ inline float bfu2f(unsigned short u) {
  unsigned int x = ((unsigned int)u) << 16;
  return __builtin_bit_cast(float, x);
}
__device__ inline unsigned int pack2bf(float a, float b) {
  return (unsigned int)f2bf(a) | ((unsigned int)f2bf(b) << 16);
}
__device__ inline void glds16(const void* g, void* l) {
  __builtin_amdgcn_global_load_lds(
      (const __attribute__((address_space(1))) unsigned int*)g,
      (__attribute__((address_space(3))) unsigned int*)l, 16, 0, 0);
}

// ---------------- fused f32 -> bf16 casts (5 segments, 1 launch) --------------
__global__ __launch_bounds__(256) void cast_all_kernel(
    const float* __restrict__ x, const float* __restrict__ wq,
    const float* __restrict__ wkva, const float* __restrict__ wkvb,
    const float* __restrict__ wo,
    __hip_bfloat16* __restrict__ xb, __hip_bfloat16* __restrict__ wqb,
    __hip_bfloat16* __restrict__ wkvab, __hip_bfloat16* __restrict__ wkvbb,
    __hip_bfloat16* __restrict__ wob) {
  const int bid = blockIdx.x;
  const float* src; __hip_bfloat16* dst; int n, npad, b0, nb;
  if (bid < 771)       { src = x;    dst = xb;    n = 8388608; npad = 8388608; b0 = 0;    nb = 771; }
  else if (bid < 1349) { src = wq;   dst = wqb;   n = 6291456; npad = 6291456; b0 = 771;  nb = 578; }
  else if (bid < 1469) { src = wkva; dst = wkvab; n = 1179648; npad = 1572864; b0 = 1349; nb = 120; }
  else if (bid < 1662) { src = wkvb; dst = wkvbb; n = 2097152; npad = 2097152; b0 = 1469; nb = 193; }
  else                 { src = wo;   dst = wob;   n = 4194304; npad = 4194304; b0 = 1662; nb = 386; }
  const int tid = (bid - b0) * 256 + threadIdx.x;
  const int stride = nb * 256;
  for (int i = tid * 4; i < npad; i += stride * 4) {
    if (i + 3 < n) {
      f32x4 v = *(const f32x4*)(src + i);
      dst[i + 0] = __float2bfloat16(v.x);
      dst[i + 1] = __float2bfloat16(v.y);
      dst[i + 2] = __float2bfloat16(v.z);
      dst[i + 3] = __float2bfloat16(v.w);
    } else {
#pragma unroll
      for (int z = 0; z < 4; z++)
        dst[i + z] = __float2bfloat16((i + z < n) ? src[i + z] : 0.f);
    }
  }
}

// ------------- 256x256 8-wave pipelined GEMM (R13, known-good) ----------------
template<int OUT_BF16>
__global__ __launch_bounds__(512, 2) void gemm_bt256(
    const __hip_bfloat16* __restrict__ A, const __hip_bfloat16* __restrict__ Bw,
    void* __restrict__ Cp, int M, int N, int K, int nbx) {
  __shared__ alignas(16) unsigned short Asl[2][256 * 64];  // 64 KB
  __shared__ alignas(16) unsigned short Bsl[2][256 * 64];  // 64 KB

  const int nwg = gridDim.x;
  const int cpx = nwg >> 3;
  const int id  = (blockIdx.x & 7) * cpx + (blockIdx.x >> 3);  // XCD chunking
  const int bx = id % nbx, by = id / nbx;
  const int m0 = by * 256, n0 = bx * 256;

  const int tid = threadIdx.x, w = tid >> 6, lane = tid & 63;
  const int wr = w >> 2, wc = w & 3;
  const int ml = lane & 15, quad = lane >> 4;
  const int srow = w * 8 + (lane >> 3);
  const int scol = ((lane & 7) ^ (lane >> 3)) * 8;  // pre-swizzled source chunk

  const unsigned short* Ag = (const unsigned short*)A + (size_t)(m0 + srow) * K + scol;
  const unsigned short* Bg = (const unsigned short*)Bw + (size_t)(n0 + srow) * K + scol;

  f32x4 acc[8][4];
#pragma unroll
  for (int i = 0; i < 8; i++)
#pragma unroll
    for (int j = 0; j < 4; j++)
#pragma unroll
      for (int e = 0; e < 4; e++) acc[i][j][e] = 0.0f;

  auto stage = [&](int slot, int k0) {
#pragma unroll
    for (int j = 0; j < 4; j++)
      glds16(Ag + (size_t)j * 64 * K + k0, &Asl[slot][(j * 64 + w * 8) * 64]);
#pragma unroll
    for (int j = 0; j < 4; j++)
      glds16(Bg + (size_t)j * 64 * K + k0, &Bsl[slot][(j * 64 + w * 8) * 64]);
  };

  const int nt = K / 64;
  stage(0, 0);
  stage(1, 64);
  asm volatile("s_waitcnt vmcnt(8)" ::: "memory");
  __builtin_amdgcn_s_barrier();
  asm volatile("" ::: "memory");

  int slot = 0;
  for (int t = 0; t < nt; ++t) {
    const unsigned short* As = &Asl[slot][0];
    const unsigned short* Bs = &Bsl[slot][0];

    bf16x8 bfr[2][2][2];
#pragma unroll
    for (int nh = 0; nh < 2; nh++)
#pragma unroll
      for (int nf = 0; nf < 2; nf++) {
        int r = wc * 64 + nh * 32 + nf * 16 + ml;
        const char* rowp = (const char*)&Bs[r * 64];
#pragma unroll
        for (int ks = 0; ks < 2; ks++)
          bfr[nh][nf][ks] =
              *(const bf16x8*)(rowp + ((ks * 64 + quad * 16) ^ ((ml & 7) << 4)));
      }
#pragma unroll
    for (int mh = 0; mh < 2; mh++) {
      bf16x8 af[4][2];
#pragma unroll
      for (int mf = 0; mf < 4; mf++) {
        int r = wr * 128 + mh * 64 + mf * 16 + ml;
        const char* rowp = (const char*)&As[r * 64];
#pragma unroll
        for (int ks = 0; ks < 2; ks++)
          af[mf][ks] =
              *(const bf16x8*)(rowp + ((ks * 64 + quad * 16) ^ ((ml & 7) << 4)));
      }
      __builtin_amdgcn_s_setprio(1);
#pragma unroll
      for (int nh = 0; nh < 2; nh++)
#pragma unroll
        for (int mf = 0; mf < 4; mf++)
#pragma unroll
          for (int nf = 0; nf < 2; nf++)
#pragma unroll
            for (int ks = 0; ks < 2; ks++)
              acc[mh * 4 + mf][nh * 2 + nf] = __builtin_amdgcn_mfma_f32_16x16x32_bf16(
                  af[mf][ks], bfr[nh][nf][ks], acc[mh * 4 + mf][nh * 2 + nf], 0, 0, 0);
      __builtin_amdgcn_s_setprio(0);
    }

    asm volatile("" ::: "memory");
    __builtin_amdgcn_s_barrier();
    asm volatile("" ::: "memory");
    if (t + 2 < nt) {
      stage(slot, (t + 2) * 64);
      asm volatile("s_waitcnt vmcnt(8)" ::: "memory");
    } else {
      asm volatile("s_waitcnt vmcnt(0)" ::: "memory");
    }
    __builtin_amdgcn_s_barrier();
    asm volatile("" ::: "memory");
    slot ^= 1;
  }

#pragma unroll
  for (int mi = 0; mi < 8; mi++) {
#pragma unroll
    for (int ni = 0; ni < 4; ni++) {
      int col = n0 + wc * 64 + ni * 16 + ml;
      int rowb = m0 + wr * 128 + mi * 16 + quad * 4;
#pragma unroll
      for (int j = 0; j < 4; j++) {
        float v = acc[mi][ni][j];
        if (OUT_BF16)
          ((__hip_bfloat16*)Cp)[(size_t)(rowb + j) * N + col] = __float2bfloat16(v);
        else
          ((float*)Cp)[(size_t)(rowb + j) * N + col] = v;
      }
    }
  }
}

// ---- 256x128-tile variant (same template; BN=128): grid (N/128)*(M/256) -----
// Stage = 6 loads (4A + 2B) -> vmcnt(6) gate. LDS 96 KB. acc 8x2.
template<int OUT_BF16>
__global__ __launch_bounds__(512, 1) void gemm_bt256x128(
    const __hip_bfloat16* __restrict__ A, const __hip_bfloat16* __restrict__ Bw,
    void* __restrict__ Cp, int M, int N, int K, int nbx) {
  __shared__ alignas(16) unsigned short Asl[2][256 * 64];  // 64 KB
  __shared__ alignas(16) unsigned short Bsl[2][128 * 64];  // 32 KB

  const int nwg = gridDim.x;
  const int cpx = nwg >> 3;
  const int id  = (blockIdx.x & 7) * cpx + (blockIdx.x >> 3);  // XCD chunking
  const int bx = id % nbx, by = id / nbx;
  const int m0 = by * 256, n0 = bx * 128;

  const int tid = threadIdx.x, w = tid >> 6, lane = tid & 63;
  const int wr = w >> 2, wc = w & 3;            // 2(M) x 4(N); wave covers 128x32
  const int ml = lane & 15, quad = lane >> 4;
  const int srow = w * 8 + (lane >> 3);
  const int scol = ((lane & 7) ^ (lane >> 3)) * 8;  // pre-swizzled source chunk

  const unsigned short* Ag = (const unsigned short*)A + (size_t)(m0 + srow) * K + scol;
  const unsigned short* Bg = (const unsigned short*)Bw + (size_t)(n0 + srow) * K + scol;

  f32x4 acc[8][2];
#pragma unroll
  for (int i = 0; i < 8; i++)
#pragma unroll
    for (int j = 0; j < 2; j++)
#pragma unroll
      for (int e = 0; e < 4; e++) acc[i][j][e] = 0.0f;

  auto stage = [&](int slot, int k0) {
#pragma unroll
    for (int j = 0; j < 4; j++)
      glds16(Ag + (size_t)j * 64 * K + k0, &Asl[slot][(j * 64 + w * 8) * 64]);
#pragma unroll
    for (int j = 0; j < 2; j++)
      glds16(Bg + (size_t)j * 64 * K + k0, &Bsl[slot][(j * 64 + w * 8) * 64]);
  };

  const int nt = K / 64;
  stage(0, 0);
  stage(1, 64);
  asm volatile("s_waitcnt vmcnt(6)" ::: "memory");  // slot0 (oldest 6) landed
  __builtin_amdgcn_s_barrier();
  asm volatile("" ::: "memory");

  int slot = 0;
  for (int t = 0; t < nt; ++t) {
    const unsigned short* As = &Asl[slot][0];
    const unsigned short* Bs = &Bsl[slot][0];

    bf16x8 bfr[2][2];  // [nf][ks]; wave cols = wc*32 + nf*16 + ml
#pragma unroll
    for (int nf = 0; nf < 2; nf++) {
      int r = wc * 32 + nf * 16 + ml;
      const char* rowp = (const char*)&Bs[r * 64];
#pragma unroll
      for (int ks = 0; ks < 2; ks++)
        bfr[nf][ks] =
            *(const bf16x8*)(rowp + ((ks * 64 + quad * 16) ^ ((ml & 7) << 4)));
    }
#pragma unroll
    for (int mh = 0; mh < 2; mh++) {
      bf16x8 af[4][2];
#pragma unroll
      for (int mf = 0; mf < 4; mf++) {
        int r = wr * 128 + mh * 64 + mf * 16 + ml;
        const char* rowp = (const char*)&As[r * 64];
#pragma unroll
        for (int ks = 0; ks < 2; ks++)
          af[mf][ks] =
              *(const bf16x8*)(rowp + ((ks * 64 + quad * 16) ^ ((ml & 7) << 4)));
      }
      __builtin_amdgcn_s_setprio(1);
#pragma unroll
      for (int mf = 0; mf < 4; mf++)
#pragma unroll
        for (int nf = 0; nf < 2; nf++)
#pragma unroll
          for (int ks = 0; ks < 2; ks++)
            acc[mh * 4 + mf][nf] = __builtin_amdgcn_mfma_f32_16x16x32_bf16(
                af[mf][ks], bfr[nf][ks], acc[mh * 4 + mf][nf], 0, 0, 0);
      __builtin_amdgcn_s_setprio(0);
    }

    asm volatile("" ::: "memory");
    __builtin_amdgcn_s_barrier();
    asm volatile("" ::: "memory");
    if (t + 2 < nt) {
      stage(slot, (t + 2) * 64);
      asm volatile("s_waitcnt vmcnt(6)" ::: "memory");
    } else {
      asm volatile("s_waitcnt vmcnt(0)" ::: "memory");
    }
    __builtin_amdgcn_s_barrier();
    asm volatile("" ::: "memory");
    slot ^= 1;
  }

#pragma unroll
  for (int mi = 0; mi < 8; mi++) {
#pragma unroll
    for (int ni = 0; ni < 2; ni++) {
      int col = n0 + wc * 32 + ni * 16 + ml;
      int rowb = m0 + wr * 128 + mi * 16 + quad * 4;
#pragma unroll
      for (int j = 0; j < 4; j++) {
        float v = acc[mi][ni][j];
        if (OUT_BF16)
          ((__hip_bfloat16*)Cp)[(size_t)(rowb + j) * N + col] = __float2bfloat16(v);
        else
          ((float*)Cp)[(size_t)(rowb + j) * N + col] = v;
      }
    }
  }
}

// --- merged: RoPE(q_pe) in place + RMSNorm(kv latent) + RoPE(k_pe) -----------
__global__ __launch_bounds__(256) void rope_rms_kernel(
    __hip_bfloat16* __restrict__ qkv, const float* __restrict__ w,
    const float* __restrict__ freqs, __hip_bfloat16* __restrict__ latent,
    __hip_bfloat16* __restrict__ kpe_out) {
  int si = blockIdx.x;
  int s  = si & (S_LEN - 1);
  int tid = threadIdx.x;
#pragma unroll
  for (int p = tid; p < NH * 32; p += 256) {
    int h = p >> 5, i = p & 31;
    size_t base = (size_t)si * QSTR + h * DQK + 128 + 2 * i;
    float c  = freqs[s * 64 + 2 * i];
    float sn = freqs[s * 64 + 2 * i + 1];
    float x0 = __bfloat162float(qkv[base]);
    float x1 = __bfloat162float(qkv[base + 1]);
    qkv[base]     = __float2bfloat16(x0 * c - x1 * sn);
    qkv[base + 1] = __float2bfloat16(x0 * sn + x1 * c);
  }
  const unsigned short* row = (const unsigned short*)qkv + (size_t)si * QSTR + 3072;
  float v0 = bfu2f(row[tid]), v1 = bfu2f(row[tid + 256]);
  float ss = v0 * v0 + v1 * v1;
#pragma unroll
  for (int off = 1; off < 64; off <<= 1) ss += __shfl_xor(ss, off, 64);
  __shared__ float red[4];
  if ((tid & 63) == 0) red[tid >> 6] = ss;
  __syncthreads();
  float tot = red[0] + red[1] + red[2] + red[3];
  float r = rsqrtf(tot / 512.0f + 1e-6f);
  latent[(size_t)si * 512 + tid]       = __float2bfloat16(v0 * r * w[tid]);
  latent[(size_t)si * 512 + tid + 256] = __float2bfloat16(v1 * r * w[tid + 256]);
  if (tid < 32) {
    float c  = freqs[s * 64 + 2 * tid];
    float sn = freqs[s * 64 + 2 * tid + 1];
    float x0 = bfu2f(row[512 + 2 * tid]), x1 = bfu2f(row[512 + 2 * tid + 1]);
    kpe_out[(size_t)si * 64 + 2 * tid]     = __float2bfloat16(x0 * c - x1 * sn);
    kpe_out[(size_t)si * 64 + 2 * tid + 1] = __float2bfloat16(x0 * sn + x1 * c);
  }
}

// ---------------- 32x32-fragment MFMA flash attention (R14, best) -------------
__global__ __launch_bounds__(512, 2) void attn_mfma_kernel(
    const __hip_bfloat16* __restrict__ qb,    // fused qkv [BS][QSTR]
    const __hip_bfloat16* __restrict__ kvup,  // [BS][NH*256] (nope|v per head)
    const __hip_bfloat16* __restrict__ kpe,   // [BS][64] bf16
    unsigned short* __restrict__ op0,         // partial O half0 [BS][NH][128] bf16
    unsigned short* __restrict__ op1,         // partial O half1
    float* __restrict__ mlp0,                 // [BS*NH][2] {m,l} half0
    float* __restrict__ mlp1) {               // half1
  constexpr int KS = 200;
  constexpr int VS = 36;
  __shared__ alignas(16) unsigned short Ks[2][64 * KS];
  __shared__ alignas(16) unsigned int   Vt2[2][128 * VS];

  const int id = blockIdx.x;
  const int x  = id >> 5;
  const int hb = id & 31;
  const int h  = hb >> 1, b = hb & 1;

  const int tid = threadIdx.x, wave = tid >> 6, lane = tid & 63;
  const int l31 = lane & 31, hh = lane >> 5;
  const float qs2 = 0.07216878364870322f * 1.4426950408889634f;  // scale*log2e

  const int m16 = tid & 15;
  const int hp  = tid >> 4;
  const int vkey = (m16 & 7) << 2;
  const unsigned short* kvbase = (const unsigned short*)kvup;
  const unsigned short* kpbase = (const unsigned short*)kpe;

  int kr_[3], kc_[3];
#pragma unroll
  for (int it = 0; it < 3; it++) {
    int slot = tid + it * 512;
    kr_[it] = slot / 24;
    kc_[it] = slot - kr_[it] * 24;
  }

#pragma unroll 1
  for (int item = 0; item < 2; ++item) {
    const int qt2    = item ? (7 - x) : x;
    const int kstart = item ? (2 * qt2 + 2) : 0;
    const int kend   = kstart + 2 * qt2 + 2;
    const int qwb = qt2 * 256 + wave * 32;
    const int qg  = qwb + l31;

    bf16x8 Qf[12];
    {
      const unsigned short* qrow = (const unsigned short*)qb +
          (size_t)(b * S_LEN + qg) * QSTR + h * DQK;
#pragma unroll
      for (int s = 0; s < 12; s++)
        Qf[s] = *(const bf16x8*)(qrow + s * 16 + hh * 8);
    }

    float m_i = -1e30f, l_i = 0.0f;
    f32x16 O2[4];
#pragma unroll
    for (int mt = 0; mt < 4; mt++)
#pragma unroll
      for (int j = 0; j < 16; j++) O2[mt][j] = 0.0f;

    us8 Kpre[3], Vpre[2];

    const unsigned short* kptr[3];
    int kstep[3];
#pragma unroll
    for (int it = 0; it < 3; it++) {
      if (kc_[it] < 16) {
        kptr[it] = kvbase + (size_t)(b * S_LEN + kstart * 64 + kr_[it]) * (NH * 256)
                   + h * 256 + kc_[it] * 8;
        kstep[it] = 64 * NH * 256;
      } else {
        kptr[it] = kpbase + (size_t)(b * S_LEN + kstart * 64 + kr_[it]) * 64
                   + (kc_[it] - 16) * 8;
        kstep[it] = 64 * 64;
      }
    }
    const unsigned short* vptr = kvbase +
        (size_t)(b * S_LEN + kstart * 64 + 2 * hp) * (NH * 256) + h * 256 + 128 + m16 * 8;

    if (item) __syncthreads();

    {
#pragma unroll
      for (int it = 0; it < 3; it++) {
        Kpre[it] = *(const us8*)kptr[it];
        kptr[it] += kstep[it];
      }
      Vpre[0] = *(const us8*)vptr;
      Vpre[1] = *(const us8*)(vptr + NH * 256);
      vptr += 64 * NH * 256;
#pragma unroll
      for (int it = 0; it < 3; it++)
        *(us8*)&Ks[0][kr_[it] * KS + kc_[it] * 8] = Kpre[it];
#pragma unroll
      for (int z = 0; z < 8; z++) {
        int d = m16 * 8 + z;
        Vt2[0][d * VS + (hp ^ vkey)] =
            (unsigned)(unsigned short)Vpre[0][z] |
            ((unsigned)(unsigned short)Vpre[1][z] << 16);
      }
      __syncthreads();
    }

    int cur = 0;
    for (int kt = kstart; kt < kend; kt++) {
      const int kb = kt * 64;
      const unsigned short* ksc = Ks[cur];
      const unsigned int*   vtc = Vt2[cur];

      const int havenext = (kt + 1 < kend);
      if (havenext) {
#pragma unroll
        for (int it = 0; it < 3; it++) {
          Kpre[it] = *(const us8*)kptr[it];
          kptr[it] += kstep[it];
        }
        Vpre[0] = *(const us8*)vptr;
        Vpre[1] = *(const us8*)(vptr + NH * 256);
        vptr += 64 * NH * 256;
      }

      if (kb <= qwb + 31) {
        f32x16 st2[2];
        __builtin_amdgcn_s_setprio(1);
#pragma unroll
        for (int mt = 0; mt < 2; mt++) {
          f32x16 acc;
#pragma unroll
          for (int j = 0; j < 16; j++) acc[j] = 0.0f;
#pragma unroll
          for (int s = 0; s < 12; s++) {
            bf16x8 kf = *(const bf16x8*)&ksc[(mt * 32 + l31) * KS + s * 16 + hh * 8];
            acc = __builtin_amdgcn_mfma_f32_32x32x16_bf16(kf, Qf[s], acc, 0, 0, 0);
          }
          st2[mt] = acc;
        }
        __builtin_amdgcn_s_setprio(0);

        if (kb + 64 > qwb) {
#pragma unroll
          for (int mt = 0; mt < 2; mt++)
#pragma unroll
            for (int r = 0; r < 16; r++) {
              int kpos = kb + mt * 32 + (r & 3) + 8 * (r >> 2) + 4 * hh;
              st2[mt][r] = (kpos > qg) ? -1e30f : st2[mt][r];
            }
        }
        float t16[16];
#pragma unroll
        for (int r = 0; r < 16; r++) t16[r] = fmaxf(st2[0][r], st2[1][r]);
#pragma unroll
        for (int sw = 8; sw >= 1; sw >>= 1)
#pragma unroll
          for (int r = 0; r < 8; r++)
            if (r < sw) t16[r] = fmaxf(t16[r], t16[r + sw]);
        float mloc = t16[0] * qs2;
        mloc = fmaxf(mloc, __shfl_xor(mloc, 32, 64));
        if (!__all(mloc <= m_i + 8.0f)) {
          float m_new = fmaxf(m_i, mloc);
          float alpha = exp2f(m_i - m_new);
          l_i *= alpha;
#pragma unroll
          for (int mt = 0; mt < 4; mt++)
#pragma unroll
            for (int j = 0; j < 16; j++) O2[mt][j] *= alpha;
          m_i = m_new;
        }
        const float nm = -m_i;
#pragma unroll
        for (int mt = 0; mt < 2; mt++)
#pragma unroll
          for (int r = 0; r < 16; r++) {
            float p = exp2f(fmaf(st2[mt][r], qs2, nm));
            st2[mt][r] = p;
          }
        float s16[16];
#pragma unroll
        for (int r = 0; r < 16; r++) s16[r] = st2[0][r] + st2[1][r];
#pragma unroll
        for (int sw = 8; sw >= 1; sw >>= 1)
#pragma unroll
          for (int r = 0; r < 8; r++)
            if (r < sw) s16[r] += s16[r + sw];
        float psum = s16[0];
        psum += __shfl_xor(psum, 32, 64);
        l_i += psum;

        bf16x8 pf[4];
#pragma unroll
        for (int ss = 0; ss < 4; ss++) {
          const int pmt = ss >> 1, gg = ss & 1;
          unsigned int U0 = pack2bf(st2[pmt][gg * 8 + 0], st2[pmt][gg * 8 + 1]);
          unsigned int U1 = pack2bf(st2[pmt][gg * 8 + 2], st2[pmt][gg * 8 + 3]);
          unsigned int U2 = pack2bf(st2[pmt][gg * 8 + 4], st2[pmt][gg * 8 + 5]);
          unsigned int U3 = pack2bf(st2[pmt][gg * 8 + 6], st2[pmt][gg * 8 + 7]);
          unsigned int E0 = __shfl_xor(hh ? U0 : U2, 32, 64);
          unsigned int E1 = __shfl_xor(hh ? U1 : U3, 32, 64);
          ui4 pd;
          pd.x = hh ? E0 : U0;
          pd.y = hh ? E1 : U1;
          pd.z = hh ? U2 : E0;
          pd.w = hh ? U3 : E1;
          pf[ss] = __builtin_bit_cast(bf16x8, pd);
        }

        __builtin_amdgcn_s_setprio(1);
#pragma unroll
        for (int ss = 0; ss < 4; ss++) {
#pragma unroll
          for (int mt = 0; mt < 4; mt++) {
            int v = mt * 32 + l31;
            const unsigned int* vp =
                &vtc[v * VS + ((ss * 8 + hh * 4) ^ (((v >> 3) & 7) << 2))];
            bf16x8 bv = *(const bf16x8*)vp;
            O2[mt] = __builtin_amdgcn_mfma_f32_32x32x16_bf16(bv, pf[ss], O2[mt],
                                                             0, 0, 0);
          }
        }
        __builtin_amdgcn_s_setprio(0);
      }

      if (havenext) {
#pragma unroll
        for (int it = 0; it < 3; it++)
          *(us8*)&Ks[cur ^ 1][kr_[it] * KS + kc_[it] * 8] = Kpre[it];
#pragma unroll
        for (int z = 0; z < 8; z++) {
          int d = m16 * 8 + z;
          Vt2[cur ^ 1][d * VS + (hp ^ vkey)] =
              (unsigned)(unsigned short)Vpre[0][z] |
              ((unsigned)(unsigned short)Vpre[1][z] << 16);
        }
        __syncthreads();
        cur ^= 1;
      }
    }

    unsigned short* op = item ? op1 : op0;
    float* mlp = item ? mlp1 : mlp0;
    const size_t basep = (size_t)(b * S_LEN + qg) * NH + h;
    unsigned short* orow = op + basep * 128;
#pragma unroll
    for (int mt = 0; mt < 4; mt++) {
#pragma unroll
      for (int g = 0; g < 4; g++) {
        us4 pk;
#pragma unroll
        for (int j = 0; j < 4; j++) pk[j] = f2bf(O2[mt][g * 4 + j]);
        *(us4*)(orow + mt * 32 + g * 8 + hh * 4) = pk;
      }
    }
    if (hh == 0) {
      mlp[basep * 2 + 0] = m_i;
      mlp[basep * 2 + 1] = l_i;
    }
  }
}

// ---------------- combine the two K-halves per q-row ---------------------------
__global__ __launch_bounds__(256) void attn_combine_kernel(
    const unsigned short* __restrict__ op0, const unsigned short* __restrict__ op1,
    const float* __restrict__ mlp0, const float* __restrict__ mlp1,
    __hip_bfloat16* __restrict__ attn_out) {
  const int bs = blockIdx.x;
  const int tid = threadIdx.x;
  const int h = tid >> 4, dc = (tid & 15) * 8;
  const size_t basep = (size_t)bs * NH + h;
  const us8 a = *(const us8*)(op0 + basep * 128 + dc);
  const us8 c = *(const us8*)(op1 + basep * 128 + dc);
  const float m0 = mlp0[basep * 2], l0 = mlp0[basep * 2 + 1];
  const float m1 = mlp1[basep * 2], l1 = mlp1[basep * 2 + 1];
  const float m = fmaxf(m0, m1);
  const float a0 = exp2f(m0 - m), a1 = exp2f(m1 - m);
  const float inv = 1.0f / (l0 * a0 + l1 * a1);
  us8 o;
#pragma unroll
  for (int z = 0; z < 8; z++) {
    float v = (bfu2f((unsigned short)a[z]) * a0 +
               bfu2f((unsigned short)c[z]) * a1) * inv;
    o[z] = f2bf(v);
  }
  *(us8*)((unsigned short*)attn_out + (size_t)bs * (NH * DV) + h * DV + dc) = o;
}

// ---------------- launch ----------------
extern "C" void kernel_launch(void* const* d_in, const int* in_sizes, int n_in,
                              void* d_out, int out_size, void* d_ws, size_t ws_size,
                              hipStream_t stream) {
  const float* x     = (const float*)d_in[0];
  const float* freqs = (const float*)d_in[2];
  const float* wq    = (const float*)d_in[4];
  const float* wkva  = (const float*)d_in[5];
  const float* wkvb  = (const float*)d_in[6];
  const float* wo    = (const float*)d_in[7];
  const float* kvnw  = (const float*)d_in[8];
  float* out = (float*)d_out;

  char* ws = (char*)d_ws;
  size_t off = 0;
  auto alloc = [&](size_t bytes) {
    void* p = ws + off;
    off += (bytes + 255) & ~(size_t)255;
    return p;
  };
  __hip_bfloat16* x_bf    = (__hip_bfloat16*)alloc((size_t)BS_TOT * 2048 * 2);
  __hip_bfloat16* wq_bf   = (__hip_bfloat16*)alloc((size_t)3072 * 2048 * 2);
  __hip_bfloat16* wkva_bf = (__hip_bfloat16*)alloc((size_t)768 * 2048 * 2);  // contiguous with wq_bf -> 3840 rows
  __hip_bfloat16* wkvb_bf = (__hip_bfloat16*)alloc((size_t)4096 * 512 * 2);
  __hip_bfloat16* wo_bf   = (__hip_bfloat16*)alloc((size_t)2048 * 2048 * 2);
  __hip_bfloat16* qkv_bf  = (__hip_bfloat16*)alloc((size_t)BS_TOT * QSTR * 2);
  __hip_bfloat16* latent  = (__hip_bfloat16*)alloc((size_t)BS_TOT * 512 * 2);
  __hip_bfloat16* kpe     = (__hip_bfloat16*)alloc((size_t)BS_TOT * 64 * 2);
  __hip_bfloat16* kvup    = (__hip_bfloat16*)alloc((size_t)BS_TOT * 4096 * 2);
  __hip_bfloat16* attn    = (__hip_bfloat16*)alloc((size_t)BS_TOT * 2048 * 2);

  unsigned short* op0 = (unsigned short*)x_bf;
  unsigned short* op1 = (unsigned short*)wq_bf;
  float* mlp0 = (float*)latent;
  float* mlp1 = mlp0 + (size_t)BS_TOT * NH * 2;

  cast_all_kernel<<<2048, 256, 0, stream>>>(x, wq, wkva, wkvb, wo,
                                            x_bf, wq_bf, wkva_bf, wkvb_bf, wo_bf);

  gemm_bt256<1><<<dim3(240), 512, 0, stream>>>(
      x_bf, wq_bf, qkv_bf, BS_TOT, QSTR, 2048, QSTR / 256);
  rope_rms_kernel<<<BS_TOT, 256, 0, stream>>>(qkv_bf, kvnw, freqs, latent, kpe);

  gemm_bt256<1><<<dim3(256), 512, 0, stream>>>(
      latent, wkvb_bf, kvup, BS_TOT, 4096, 512, 16);

  attn_mfma_kernel<<<dim3(256, 1, 1), 512, 0, stream>>>(
      qkv_bf, kvup, kpe, op0, op1, mlp0, mlp1);
  attn_combine_kernel<<<dim3(BS_TOT, 1, 1), 256, 0, stream>>>(
      op0, op1, mlp0, mlp1, attn);

  gemm_bt256x128<0><<<dim3(256), 512, 0, stream>>>(
      attn, wo_bf, out, BS_TOT, 2048, 2048, 16);
}